// Round 18
// baseline (2019.531 us; speedup 1.0000x reference)
//
#include <hip/hip_runtime.h>
#include <hip/hip_fp16.h>

namespace {

constexpr int kS = 1024;   // SEQ
constexpr int kI = 64;     // INPUT_SIZE
constexpr int kH = 128;    // HIDDEN

// fp16 weight layout in d_ws (element offsets)
constexpr int oWx1 = 0;            // [512][64]
constexpr int oWh1 = 32768;        // [512][128]
constexpr int oWx2 = 98304;        // [512][128]
constexpr int oWh2 = 163840;       // [512][128]
constexpr int nW   = 229376;

typedef _Float16 f16x8 __attribute__((ext_vector_type(8)));
typedef float    f32x4 __attribute__((ext_vector_type(4)));

#define MFMA16(a, b, c) __builtin_amdgcn_mfma_f32_16x16x32_f16((a), (b), (c), 0, 0, 0)

__device__ __forceinline__ float rcpf(float x) {
#if __has_builtin(__builtin_amdgcn_rcpf)
  return __builtin_amdgcn_rcpf(x);
#else
  return 1.0f / x;
#endif
}
__device__ __forceinline__ float sigf(float x)  { return rcpf(1.0f + __expf(-x)); }
__device__ __forceinline__ float tanhff(float x){ return 1.0f - 2.0f * rcpf(1.0f + __expf(2.0f * x)); }

template <int P>
__device__ __forceinline__ void prio() {
#if __has_builtin(__builtin_amdgcn_s_setprio)
  __builtin_amdgcn_s_setprio(P);
#endif
}

// LDS-only barrier: waits lgkmcnt(0) (LDS writes visible) then raw s_barrier.
// Crucially does NOT drain vmcnt -> global prefetch loads / h1out stores stay
// in flight across step barriers (T4: never vmcnt(0) in the main loop).
// Rule 18: sched_barrier(0) after the asm waitcnt pins compiler motion.
__device__ __forceinline__ void lbar() {
  asm volatile("s_waitcnt lgkmcnt(0)" ::: "memory");
#if __has_builtin(__builtin_amdgcn_sched_barrier)
  __builtin_amdgcn_sched_barrier(0);
#endif
  __builtin_amdgcn_s_barrier();
}

__device__ __forceinline__ unsigned packf2(float lo, float hi) {
  _Float16 a = (_Float16)lo, b = (_Float16)hi;
  unsigned short ua = __builtin_bit_cast(unsigned short, a);
  unsigned short ub = __builtin_bit_cast(unsigned short, b);
  return (unsigned)ua | ((unsigned)ub << 16);
}
__device__ __forceinline__ f16x8 ld16(const _Float16* p) {
  return *reinterpret_cast<const f16x8*>(p);
}

// ---- one-shot fp32 -> fp16 weight conversion into d_ws ----
__global__ void cvt_weights(const float* __restrict__ Wx1,
                            const float* __restrict__ Wh1,
                            const float* __restrict__ Wx2,
                            const float* __restrict__ Wh2,
                            _Float16* __restrict__ W16) {
  const int P1 = oWh1 / 2, P2 = oWx2 / 2, P3 = oWh2 / 2, PE = nW / 2;
  for (int i = blockIdx.x * blockDim.x + threadIdx.x; i < PE;
       i += gridDim.x * blockDim.x) {
    const float* s; int e;
    if (i < P1)      { s = Wx1; e = i * 2; }
    else if (i < P2) { s = Wh1; e = (i - P1) * 2; }
    else if (i < P3) { s = Wx2; e = (i - P2) * 2; }
    else             { s = Wh2; e = (i - P3) * 2; }
    const float2 v = *reinterpret_cast<const float2*>(s + e);
    *reinterpret_cast<unsigned*>(W16 + (size_t)i * 2) = packf2(v.x, v.y);
  }
}

// Structure (both kernels): 256 blocks x 512 thr (8 waves, cap 128, no-spill
// budget), chains b0,b0+1, single pass. Wave w owns tiles {a*128 + 16w} for
// gates a=0..3 (cells [16w,16w+16)); Wh resident = 16 frags = 64 VGPR.
// Per step: MFMA phase (all waves) -> g via n<2 lanes -> lbar -> DENSE
// activation (tid<256, 1 cell/thread: round-10-proven issue-efficient) ->
// lbar. Wx handled per 8-step tile as real GEMM (16 B-cols real, bias
// folded into xg). Global traffic never drains inside the step loop.
// A/B share k-chunk packing (HW k-permutation cancels); C/D mapping
// (col=lane&15, row=4*(lane>>4)+reg) is the only load-bearing layout.

// ---------------- K1: layer 1 ----------------
__global__ __launch_bounds__(512) void lstm_l1(
    const float* __restrict__ x, const _Float16* __restrict__ W16,
    const float* __restrict__ bx1, const float* __restrict__ bh1,
    _Float16* __restrict__ h1out)
{
  const int tid  = threadIdx.x;
  const int b0   = blockIdx.x * 2;
  const int w    = tid >> 6;
  const int lane = tid & 63;
  const int q    = lane >> 4;
  const int n    = lane & 15;
  const int csel = (n < 2) ? n : 0;

  __shared__ __align__(16) _Float16 xF[2][8][16][8];     // [buf][kc][col][e] 4 KiB
  __shared__ __align__(16) _Float16 hH[2][8][2][16][8];  // [buf][dt][c][kc][e] 8 KiB
  __shared__ float xg[16][516];                          // [col][row] 33 KiB
  __shared__ float g[2][512];                            // step preacts 4 KiB
  __shared__ float bls[512];                             // folded biases 2 KiB

  const _Float16* Wh = W16 + oWh1;
  const _Float16* Wx = W16 + oWx1;

  f16x8 Ah[4][4];                      // resident Wh1
#pragma unroll
  for (int a = 0; a < 4; ++a) {
    const int row = a * 128 + w * 16 + n;
#pragma unroll
    for (int kt = 0; kt < 4; ++kt)
      Ah[a][kt] = ld16(Wh + (size_t)row * kH + kt * 32 + q * 8);
  }

  bls[tid] = bx1[tid] + bh1[tid];
  if (tid < 32) {                      // zero h(-1): hH[1][7]
    uint4 z = {0u, 0u, 0u, 0u};
    reinterpret_cast<uint4*>(&hH[1][7][0][0][0])[tid] = z;
  }
  float cst = 0.f;                     // cell state (tid<256 meaningful)

  // staging geometry (same for prefetch, xF write, h dump)
  const int sdt = tid >> 6, sc = (tid >> 5) & 1;
  const int sk2 = (tid & 31) * 2, sk4 = (tid & 31) * 4;

  // prefetch x tile 0
  float2 xr = *reinterpret_cast<const float2*>(
      x + ((size_t)(b0 + sc) * kS + (size_t)sdt) * kI + sk2);

  for (int T = 0; T < 128; ++T) {
    const int buf = T & 1;
    // write staged regs -> xF[buf] (vmcnt wait here had a full tile to land)
    *reinterpret_cast<unsigned*>(&xF[buf][sk2 >> 3][sdt * 2 + sc][sk2 & 7]) =
        packf2(xr.x, xr.y);
    if (T < 127)                       // fire prefetch for tile T+1
      xr = *reinterpret_cast<const float2*>(
          x + ((size_t)(b0 + sc) * kS + (size_t)((T + 1) * 8 + sdt)) * kI + sk2);
    lbar();

    {  // tile GEMM: xg[col][row] = Wx1 . x + bias (K=64, Wx streamed)
      const char* xb = reinterpret_cast<const char*>(&xF[buf][0][0][0]);
      f32x4 e0 = {0,0,0,0}, e1 = {0,0,0,0}, e2 = {0,0,0,0}, e3 = {0,0,0,0};
#pragma unroll
      for (int kt = 0; kt < 2; ++kt) {
        const f16x8 bf = *reinterpret_cast<const f16x8*>(
            xb + (((kt * 4 + q) * 16 + n) << 4));
        e0 = MFMA16(ld16(Wx + (size_t)(0 * 128 + w * 16 + n) * kI + kt * 32 + q * 8), bf, e0);
        e1 = MFMA16(ld16(Wx + (size_t)(1 * 128 + w * 16 + n) * kI + kt * 32 + q * 8), bf, e1);
        e2 = MFMA16(ld16(Wx + (size_t)(2 * 128 + w * 16 + n) * kI + kt * 32 + q * 8), bf, e2);
        e3 = MFMA16(ld16(Wx + (size_t)(3 * 128 + w * 16 + n) * kI + kt * 32 + q * 8), bf, e3);
      }
      const int r0 = w * 16 + q * 4;
      e0 += *reinterpret_cast<const f32x4*>(&bls[r0]);
      e1 += *reinterpret_cast<const f32x4*>(&bls[128 + r0]);
      e2 += *reinterpret_cast<const f32x4*>(&bls[256 + r0]);
      e3 += *reinterpret_cast<const f32x4*>(&bls[384 + r0]);
      *reinterpret_cast<f32x4*>(&xg[n][r0])       = e0;
      *reinterpret_cast<f32x4*>(&xg[n][128 + r0]) = e1;
      *reinterpret_cast<f32x4*>(&xg[n][256 + r0]) = e2;
      *reinterpret_cast<f32x4*>(&xg[n][384 + r0]) = e3;
    }
    lbar();

    for (int dt = 0; dt < 8; ++dt) {
      const char* hb = (dt == 0)
          ? reinterpret_cast<const char*>(&hH[(T + 1) & 1][7][csel][0][0])
          : reinterpret_cast<const char*>(&hH[buf][dt - 1][csel][0][0]);
      const f16x8 bf0 = *reinterpret_cast<const f16x8*>(hb + ((0  + q) << 4));
      const f16x8 bf1 = *reinterpret_cast<const f16x8*>(hb + ((4  + q) << 4));
      const f16x8 bf2 = *reinterpret_cast<const f16x8*>(hb + ((8  + q) << 4));
      const f16x8 bf3 = *reinterpret_cast<const f16x8*>(hb + ((12 + q) << 4));

      f32x4 d0 = {0,0,0,0}, d1 = {0,0,0,0}, d2 = {0,0,0,0}, d3 = {0,0,0,0};
      prio<1>();
      d0 = MFMA16(Ah[0][0], bf0, d0);  d1 = MFMA16(Ah[1][0], bf0, d1);
      d2 = MFMA16(Ah[2][0], bf0, d2);  d3 = MFMA16(Ah[3][0], bf0, d3);
      d0 = MFMA16(Ah[0][1], bf1, d0);  d1 = MFMA16(Ah[1][1], bf1, d1);
      d2 = MFMA16(Ah[2][1], bf1, d2);  d3 = MFMA16(Ah[3][1], bf1, d3);
      d0 = MFMA16(Ah[0][2], bf2, d0);  d1 = MFMA16(Ah[1][2], bf2, d1);
      d2 = MFMA16(Ah[2][2], bf2, d2);  d3 = MFMA16(Ah[3][2], bf2, d3);
      d0 = MFMA16(Ah[0][3], bf3, d0);  d1 = MFMA16(Ah[1][3], bf3, d1);
      d2 = MFMA16(Ah[2][3], bf3, d2);  d3 = MFMA16(Ah[3][3], bf3, d3);
      prio<0>();

      if (n < 2) {                     // publish preacts (2-way bank = free)
        const int r0 = w * 16 + q * 4;
        *reinterpret_cast<f32x4*>(&g[n][r0])       = d0;
        *reinterpret_cast<f32x4*>(&g[n][128 + r0]) = d1;
        *reinterpret_cast<f32x4*>(&g[n][256 + r0]) = d2;
        *reinterpret_cast<f32x4*>(&g[n][384 + r0]) = d3;
      }
      lbar();

      if (tid < 256) {                 // DENSE activation: 1 cell/thread
        const int c = tid >> 7, j = tid & 127, col = dt * 2 + c;
        const float gi = xg[col][j]       + g[c][j];
        const float gf = xg[col][j + 128] + g[c][j + 128];
        const float gg = xg[col][j + 256] + g[c][j + 256];
        const float go = xg[col][j + 384] + g[c][j + 384];
        cst = sigf(gf) * cst + sigf(gi) * tanhff(gg);
        hH[buf][dt][c][j >> 3][j & 7] = (_Float16)(sigf(go) * tanhff(cst));
      }
      lbar();
    }

    {  // dump tile h1 -> global, fire-and-forget (never drained in loop)
      const uint2 v = *reinterpret_cast<const uint2*>(&hH[buf][sdt][sc][sk4 >> 3][sk4 & 7]);
      *reinterpret_cast<uint2*>(
          h1out + ((size_t)(b0 + sc) * kS + (size_t)(T * 8 + sdt)) * kH + sk4) = v;
    }
  }
}

// ---------------- K2: layer 2 + head ----------------
__global__ __launch_bounds__(512) void lstm_l2(
    const _Float16* __restrict__ h1in, const _Float16* __restrict__ W16,
    const float* __restrict__ bx2, const float* __restrict__ bh2,
    const float* __restrict__ Wc,  const float* __restrict__ bc,
    float* __restrict__ out)
{
  const int tid  = threadIdx.x;
  const int b0   = blockIdx.x * 2;
  const int w    = tid >> 6;
  const int lane = tid & 63;
  const int q    = lane >> 4;
  const int n    = lane & 15;
  const int csel = (n < 2) ? n : 0;

  __shared__ __align__(16) _Float16 h1F[2][16][16][8];   // [buf][kc][col][e] 8 KiB
  __shared__ __align__(16) _Float16 h2P[2][2][16][8];    // [par][c][kc][e] 1 KiB
  __shared__ float xg[16][516];                          // 33 KiB
  __shared__ float g[2][512];                            // 4 KiB
  __shared__ float bls[512];                             // 2 KiB
  __shared__ float hfin[2][128];                         // 1 KiB

  const _Float16* Wh = W16 + oWh2;
  const _Float16* Wx = W16 + oWx2;

  f16x8 Ah[4][4];
#pragma unroll
  for (int a = 0; a < 4; ++a) {
    const int row = a * 128 + w * 16 + n;
#pragma unroll
    for (int kt = 0; kt < 4; ++kt)
      Ah[a][kt] = ld16(Wh + (size_t)row * kH + kt * 32 + q * 8);
  }

  bls[tid] = bx2[tid] + bh2[tid];
  if (tid < 32) {                      // zero h2(-1): h2P[1]
    uint4 z = {0u, 0u, 0u, 0u};
    reinterpret_cast<uint4*>(&h2P[1][0][0][0])[tid] = z;
  }
  float cst = 0.f;

  const int sdt = tid >> 6, sc = (tid >> 5) & 1;
  const int sk4 = (tid & 31) * 4;

  // prefetch h1 tile 0
  uint2 hr = *reinterpret_cast<const uint2*>(
      h1in + ((size_t)(b0 + sc) * kS + (size_t)sdt) * kH + sk4);

  for (int T = 0; T < 128; ++T) {
    const int buf = T & 1;
    *reinterpret_cast<uint2*>(&h1F[buf][sk4 >> 3][sdt * 2 + sc][sk4 & 7]) = hr;
    if (T < 127)
      hr = *reinterpret_cast<const uint2*>(
          h1in + ((size_t)(b0 + sc) * kS + (size_t)((T + 1) * 8 + sdt)) * kH + sk4);
    lbar();

    {  // tile GEMM: xg = Wx2 . h1(tile) + bias (K=128, Wx streamed)
      const char* xb = reinterpret_cast<const char*>(&h1F[buf][0][0][0]);
      f32x4 e0 = {0,0,0,0}, e1 = {0,0,0,0}, e2 = {0,0,0,0}, e3 = {0,0,0,0};
#pragma unroll
      for (int kt = 0; kt < 4; ++kt) {
        const f16x8 bf = *reinterpret_cast<const f16x8*>(
            xb + (((kt * 4 + q) * 16 + n) << 4));
        e0 = MFMA16(ld16(Wx + (size_t)(0 * 128 + w * 16 + n) * kH + kt * 32 + q * 8), bf, e0);
        e1 = MFMA16(ld16(Wx + (size_t)(1 * 128 + w * 16 + n) * kH + kt * 32 + q * 8), bf, e1);
        e2 = MFMA16(ld16(Wx + (size_t)(2 * 128 + w * 16 + n) * kH + kt * 32 + q * 8), bf, e2);
        e3 = MFMA16(ld16(Wx + (size_t)(3 * 128 + w * 16 + n) * kH + kt * 32 + q * 8), bf, e3);
      }
      const int r0 = w * 16 + q * 4;
      e0 += *reinterpret_cast<const f32x4*>(&bls[r0]);
      e1 += *reinterpret_cast<const f32x4*>(&bls[128 + r0]);
      e2 += *reinterpret_cast<const f32x4*>(&bls[256 + r0]);
      e3 += *reinterpret_cast<const f32x4*>(&bls[384 + r0]);
      *reinterpret_cast<f32x4*>(&xg[n][r0])       = e0;
      *reinterpret_cast<f32x4*>(&xg[n][128 + r0]) = e1;
      *reinterpret_cast<f32x4*>(&xg[n][256 + r0]) = e2;
      *reinterpret_cast<f32x4*>(&xg[n][384 + r0]) = e3;
    }
    lbar();

    for (int dt = 0; dt < 8; ++dt) {
      const int t = T * 8 + dt;
      const char* hb = reinterpret_cast<const char*>(&h2P[(t + 1) & 1][csel][0][0]);
      const f16x8 bf0 = *reinterpret_cast<const f16x8*>(hb + ((0  + q) << 4));
      const f16x8 bf1 = *reinterpret_cast<const f16x8*>(hb + ((4  + q) << 4));
      const f16x8 bf2 = *reinterpret_cast<const f16x8*>(hb + ((8  + q) << 4));
      const f16x8 bf3 = *reinterpret_cast<const f16x8*>(hb + ((12 + q) << 4));

      f32x4 d0 = {0,0,0,0}, d1 = {0,0,0,0}, d2 = {0,0,0,0}, d3 = {0,0,0,0};
      prio<1>();
      d0 = MFMA16(Ah[0][0], bf0, d0);  d1 = MFMA16(Ah[1][0], bf0, d1);
      d2 = MFMA16(Ah[2][0], bf0, d2);  d3 = MFMA16(Ah[3][0], bf0, d3);
      d0 = MFMA16(Ah[0][1], bf1, d0);  d1 = MFMA16(Ah[1][1], bf1, d1);
      d2 = MFMA16(Ah[2][1], bf1, d2);  d3 = MFMA16(Ah[3][1], bf1, d3);
      d0 = MFMA16(Ah[0][2], bf2, d0);  d1 = MFMA16(Ah[1][2], bf2, d1);
      d2 = MFMA16(Ah[2][2], bf2, d2);  d3 = MFMA16(Ah[3][2], bf2, d3);
      d0 = MFMA16(Ah[0][3], bf3, d0);  d1 = MFMA16(Ah[1][3], bf3, d1);
      d2 = MFMA16(Ah[2][3], bf3, d2);  d3 = MFMA16(Ah[3][3], bf3, d3);
      prio<0>();

      if (n < 2) {
        const int r0 = w * 16 + q * 4;
        *reinterpret_cast<f32x4*>(&g[n][r0])       = d0;
        *reinterpret_cast<f32x4*>(&g[n][128 + r0]) = d1;
        *reinterpret_cast<f32x4*>(&g[n][256 + r0]) = d2;
        *reinterpret_cast<f32x4*>(&g[n][384 + r0]) = d3;
      }
      lbar();

      if (tid < 256) {
        const int c = tid >> 7, j = tid & 127, col = dt * 2 + c;
        const float gi = xg[col][j]       + g[c][j];
        const float gf = xg[col][j + 128] + g[c][j + 128];
        const float gg = xg[col][j + 256] + g[c][j + 256];
        const float go = xg[col][j + 384] + g[c][j + 384];
        cst = sigf(gf) * cst + sigf(gi) * tanhff(gg);
        const float h = sigf(go) * tanhff(cst);
        h2P[t & 1][c][j >> 3][j & 7] = (_Float16)h;
        if (t == kS - 1) hfin[c][j] = h;
      }
      lbar();
    }
  }

  // classifier head: logits[b0+c, m] = Wc[m,:] . h2fin[c] + bc[m]
  if (tid < 8) {
    const int m = tid & 3, c = tid >> 2;
    const float* wr = Wc + (size_t)m * kH;
    float s0 = 0.f, s1 = 0.f, s2 = 0.f, s3 = 0.f;
#pragma unroll
    for (int j = 0; j < kH; j += 4) {
      s0 = fmaf(wr[j],     hfin[c][j],     s0);
      s1 = fmaf(wr[j + 1], hfin[c][j + 1], s1);
      s2 = fmaf(wr[j + 2], hfin[c][j + 2], s2);
      s3 = fmaf(wr[j + 3], hfin[c][j + 3], s3);
    }
    out[(size_t)(b0 + c) * 4 + m] = bc[m] + ((s0 + s1) + (s2 + s3));
  }
}

} // namespace

extern "C" void kernel_launch(void* const* d_in, const int* in_sizes, int n_in,
                              void* d_out, int out_size, void* d_ws, size_t ws_size,
                              hipStream_t stream) {
  const float* x   = (const float*)d_in[0];
  const float* Wx1 = (const float*)d_in[1];
  const float* bx1 = (const float*)d_in[2];
  const float* Wh1 = (const float*)d_in[3];
  const float* bh1 = (const float*)d_in[4];
  const float* Wx2 = (const float*)d_in[5];
  const float* bx2 = (const float*)d_in[6];
  const float* Wh2 = (const float*)d_in[7];
  const float* bh2 = (const float*)d_in[8];
  const float* Wc  = (const float*)d_in[9];
  const float* bc  = (const float*)d_in[10];

  _Float16* W16 = (_Float16*)d_ws;          // 448 KiB fp16 weights
  _Float16* h1  = (_Float16*)d_ws + nW;     // 128 MiB layer-1 stream

  hipLaunchKernelGGL(cvt_weights, dim3(448), dim3(256), 0, stream,
                     Wx1, Wh1, Wx2, Wh2, W16);
  hipLaunchKernelGGL(lstm_l1, dim3(256), dim3(512), 0, stream,
                     x, W16, bx1, bh1, h1);
  hipLaunchKernelGGL(lstm_l2, dim3(256), dim3(512), 0, stream,
                     h1, W16, bx2, bh2, Wc, bc, (float*)d_out);
}